// Round 1
// baseline (1647.098 us; speedup 1.0000x reference)
//
#include <hip/hip_runtime.h>
#include <cstddef>
#include <cstdint>

constexpr int GNUM = 262144;
constexpr int MNUM = 40962;
constexpr float LN_EPS = 1e-5f;

// ---------- int -> float passthrough ----------
__global__ void i2f_kernel(const int* __restrict__ in, float* __restrict__ out, int n4) {
  int i = blockIdx.x * 256 + threadIdx.x;
  if (i < n4) {
    int4 v = ((const int4*)in)[i];
    ((float4*)out)[i] = make_float4((float)v.x, (float)v.y, (float)v.z, (float)v.w);
  }
}

// ---------- h0 = concat(mx, zeros) [MNUM, 256] ----------
__global__ void init_h0_kernel(const float* __restrict__ mx, float* __restrict__ h0, int m) {
  int i = blockIdx.x * 256 + threadIdx.x;  // one float4 per thread
  int total = m * 64;                      // 256 floats / 4 per row
  if (i >= total) return;
  int row = i >> 6;
  int c4 = i & 63;
  float4 v;
  if (c4 < 32) v = ((const float4*)mx)[row * 32 + c4];
  else v = make_float4(0.f, 0.f, 0.f, 0.f);
  ((float4*)h0)[i] = v;
}

// ---------- scatter-add edges onto h0[:, 128:256] ----------
__global__ void scatter_kernel(const float* __restrict__ ex, const int* __restrict__ col,
                               float* __restrict__ h0, int E) {
  int e = blockIdx.x * 2 + (threadIdx.x >> 7);
  int c = threadIdx.x & 127;
  if (e >= E) return;
  int m = col[e];
  unsafeAtomicAdd(&h0[(size_t)m * 256 + 128 + c], ex[(size_t)e * 128 + c]);
}

// ---------- tiled f32 GEMM: C[M,N] = act(A[M,K] @ B[K,N] + bias) ----------
// 64x64 tile, TK=16, 256 threads, 4x4 micro-tile.
// SUMS: accumulate per-block sum(x), sum(x^2) into partials[2*pid].
template<int SILU, int SUMS>
__global__ __launch_bounds__(256) void gemm_f32_kernel(
    const float* __restrict__ A, int lda,
    const float* __restrict__ B, const float* __restrict__ bias,
    float* __restrict__ C, int ldc,
    int M, int N, int K,
    double* __restrict__ partials)
{
  __shared__ float As[16][64];
  __shared__ float Bs[16][64];
  const int t = threadIdx.x;
  const int tx = t & 15, ty = t >> 4;
  const int m0 = blockIdx.y * 64, n0 = blockIdx.x * 64;
  const int ar = t >> 2, ak = (t & 3) << 2;   // A-tile load: row, k-offset
  const int bk = t >> 4, bn = (t & 15) << 2;  // B-tile load
  const int arow = m0 + ar;
  float acc[4][4] = {};

  for (int k0 = 0; k0 < K; k0 += 16) {
    float4 av = make_float4(0.f, 0.f, 0.f, 0.f);
    if (arow < M) av = *(const float4*)(A + (size_t)arow * lda + k0 + ak);
    float4 bv = *(const float4*)(B + (size_t)(k0 + bk) * N + n0 + bn);
    __syncthreads();
    As[ak + 0][ar] = av.x; As[ak + 1][ar] = av.y;
    As[ak + 2][ar] = av.z; As[ak + 3][ar] = av.w;
    *(float4*)(&Bs[bk][bn]) = bv;
    __syncthreads();
#pragma unroll
    for (int kk = 0; kk < 16; ++kk) {
      float4 a4 = *(const float4*)(&As[kk][ty << 2]);
      float4 b4 = *(const float4*)(&Bs[kk][tx << 2]);
      float a[4] = {a4.x, a4.y, a4.z, a4.w};
      float b[4] = {b4.x, b4.y, b4.z, b4.w};
#pragma unroll
      for (int i = 0; i < 4; ++i)
#pragma unroll
        for (int j = 0; j < 4; ++j)
          acc[i][j] += a[i] * b[j];
    }
  }

  float bsv[4];
#pragma unroll
  for (int j = 0; j < 4; ++j) bsv[j] = bias[n0 + (tx << 2) + j];

  float s1 = 0.f, s2 = 0.f;
#pragma unroll
  for (int i = 0; i < 4; ++i) {
    int r = m0 + (ty << 2) + i;
    if (r < M) {
      float vv[4];
#pragma unroll
      for (int j = 0; j < 4; ++j) {
        float x = acc[i][j] + bsv[j];
        if (SILU) x = x / (1.f + __expf(-x));
        vv[j] = x;
        if (SUMS) { s1 += x; s2 += x * x; }
      }
      *(float4*)(C + (size_t)r * ldc + n0 + (tx << 2)) =
          make_float4(vv[0], vv[1], vv[2], vv[3]);
    }
  }

  if (SUMS) {
    __shared__ double red[256];
    red[t] = (double)s1;
    __syncthreads();
    for (int s = 128; s > 0; s >>= 1) { if (t < s) red[t] += red[t + s]; __syncthreads(); }
    double rs1 = red[0];
    __syncthreads();
    red[t] = (double)s2;
    __syncthreads();
    for (int s = 128; s > 0; s >>= 1) { if (t < s) red[t] += red[t + s]; __syncthreads(); }
    if (t == 0) {
      int pid = blockIdx.y * gridDim.x + blockIdx.x;
      partials[2 * pid] = rs1;
      partials[2 * pid + 1] = red[0];
    }
  }
}

// ---------- reduce partials -> (mu, rsqrt(var+eps)) ----------
__global__ void ln_finalize_kernel(const double* __restrict__ partials, int nb,
                                   double inv_count, float* __restrict__ stats) {
  __shared__ double r1[256], r2[256];
  int t = threadIdx.x;
  double s1 = 0.0, s2 = 0.0;
  for (int i = t; i < nb; i += 256) { s1 += partials[2 * i]; s2 += partials[2 * i + 1]; }
  r1[t] = s1; r2[t] = s2;
  __syncthreads();
  for (int s = 128; s > 0; s >>= 1) {
    if (t < s) { r1[t] += r1[t + s]; r2[t] += r2[t + s]; }
    __syncthreads();
  }
  if (t == 0) {
    double mu = r1[0] * inv_count;
    double var = r2[0] * inv_count - mu * mu;
    stats[0] = (float)mu;
    stats[1] = (float)(1.0 / sqrt(var + (double)LN_EPS));
  }
}

// ---------- out = base + (x - mu)*rs*w + b   (x in-place in out buffer) ----------
__global__ void ln_apply_kernel(const float* __restrict__ base, float* __restrict__ x,
                                const float* __restrict__ w, const float* __restrict__ b,
                                const float* __restrict__ stats, int n4) {
  int i = blockIdx.x * 256 + threadIdx.x;
  if (i >= n4) return;
  float mu = stats[0], rs = stats[1];
  float4 xv = ((const float4*)x)[i];
  float4 bv = ((const float4*)base)[i];
  float4 wv = ((const float4*)w)[i];
  float4 bb = ((const float4*)b)[i];
  float4 o;
  o.x = bv.x + (xv.x - mu) * rs * wv.x + bb.x;
  o.y = bv.y + (xv.y - mu) * rs * wv.y + bb.y;
  o.z = bv.z + (xv.z - mu) * rs * wv.z + bb.z;
  o.w = bv.w + (xv.w - mu) * rs * wv.w + bb.w;
  ((float4*)x)[i] = o;
}

extern "C" void kernel_launch(void* const* d_in, const int* in_sizes, int n_in,
                              void* d_out, int out_size, void* d_ws, size_t ws_size,
                              hipStream_t stream) {
  const float* gx      = (const float*)d_in[0];
  const float* mx      = (const float*)d_in[1];
  const int*   me_i    = (const int*)d_in[2];
  const float* me_x    = (const float*)d_in[3];
  const int*   g2me_i  = (const int*)d_in[4];
  const float* g2me_x  = (const float*)d_in[5];
  const int*   m2ge_i  = (const int*)d_in[6];
  const float* m2ge_x  = (const float*)d_in[7];
  const float* agg_w1  = (const float*)d_in[8];
  const float* agg_b1  = (const float*)d_in[9];
  const float* agg_w2  = (const float*)d_in[10];
  const float* agg_b2  = (const float*)d_in[11];
  const float* agg_w3  = (const float*)d_in[12];
  const float* agg_b3  = (const float*)d_in[13];
  const float* agg_ln_w = (const float*)d_in[14];
  const float* agg_ln_b = (const float*)d_in[15];
  const float* grid_w1 = (const float*)d_in[16];
  const float* grid_b1 = (const float*)d_in[17];
  const float* grid_w2 = (const float*)d_in[18];
  const float* grid_b2 = (const float*)d_in[19];
  const float* grid_ln_w = (const float*)d_in[20];
  const float* grid_ln_b = (const float*)d_in[21];

  float* out = (float*)d_out;
  size_t off[9]; off[0] = 0;
  for (int i = 0; i < 8; ++i) off[i + 1] = off[i] + (size_t)in_sizes[i];
  float* out_gx  = out + off[0];
  float* out_mx  = out + off[1];
  float* out_mei = out + off[2];
  float* out_mex = out + off[3];
  float* out_g2i = out + off[4];
  float* out_g2x = out + off[5];
  float* out_m2i = out + off[6];
  float* out_m2x = out + off[7];

  const int E = in_sizes[4] / 2;

  // ---- workspace carve (~202 MB) ----
  char* wp = (char*)d_ws;
  auto carve = [&](size_t bytes) -> void* {
    void* p = (void*)wp;
    wp += (bytes + 255) & ~(size_t)255;
    return p;
  };
  float* stats_m = (float*)carve(2 * sizeof(float));
  float* stats_g = (float*)carve(2 * sizeof(float));
  const int MB_TILES = (MNUM + 63) / 64;               // 641
  double* part_m = (double*)carve((size_t)MB_TILES * 2 * 2 * sizeof(double));
  const int CH = 32768;
  const int NCH = GNUM / CH;                           // 8
  double* part_g = (double*)carve((size_t)NCH * (CH / 64) * 2 * 2 * sizeof(double));
  float* h0 = (float*)carve((size_t)MNUM * 256 * 4);
  float* h1 = (float*)carve((size_t)MNUM * 512 * 4);
  float* h2 = (float*)carve((size_t)MNUM * 256 * 4);
  float* g1 = (float*)carve((size_t)CH * 256 * 4);

  // ---- passthrough outputs ----
  hipMemcpyAsync(out_mex, me_x,   (size_t)in_sizes[3] * 4, hipMemcpyDeviceToDevice, stream);
  hipMemcpyAsync(out_g2x, g2me_x, (size_t)in_sizes[5] * 4, hipMemcpyDeviceToDevice, stream);
  hipMemcpyAsync(out_m2x, m2ge_x, (size_t)in_sizes[7] * 4, hipMemcpyDeviceToDevice, stream);
  i2f_kernel<<<(in_sizes[2] / 4 + 255) / 256, 256, 0, stream>>>(me_i,   out_mei, in_sizes[2] / 4);
  i2f_kernel<<<(in_sizes[4] / 4 + 255) / 256, 256, 0, stream>>>(g2me_i, out_g2i, in_sizes[4] / 4);
  i2f_kernel<<<(in_sizes[6] / 4 + 255) / 256, 256, 0, stream>>>(m2ge_i, out_m2i, in_sizes[6] / 4);

  // ---- mesh path ----
  init_h0_kernel<<<(MNUM * 64 + 255) / 256, 256, 0, stream>>>(mx, h0, MNUM);
  scatter_kernel<<<(E + 1) / 2, 256, 0, stream>>>(g2me_x, g2me_i + E, h0, E);
  gemm_f32_kernel<1, 0><<<dim3(8, MB_TILES), 256, 0, stream>>>(
      h0, 256, agg_w1, agg_b1, h1, 512, MNUM, 512, 256, nullptr);
  gemm_f32_kernel<1, 0><<<dim3(4, MB_TILES), 256, 0, stream>>>(
      h1, 512, agg_w2, agg_b2, h2, 256, MNUM, 256, 512, nullptr);
  gemm_f32_kernel<0, 1><<<dim3(2, MB_TILES), 256, 0, stream>>>(
      h2, 256, agg_w3, agg_b3, out_mx, 128, MNUM, 128, 256, part_m);
  ln_finalize_kernel<<<1, 256, 0, stream>>>(part_m, MB_TILES * 2,
                                            1.0 / ((double)MNUM * 128.0), stats_m);
  ln_apply_kernel<<<(MNUM * 128 / 4 + 255) / 256, 256, 0, stream>>>(
      mx, out_mx, agg_ln_w, agg_ln_b, stats_m, MNUM * 128 / 4);

  // ---- grid path (chunked to bound ws) ----
  for (int c = 0; c < NCH; ++c) {
    const float* Ac = gx + (size_t)c * CH * 128;
    gemm_f32_kernel<1, 0><<<dim3(4, CH / 64), 256, 0, stream>>>(
        Ac, 128, grid_w1, grid_b1, g1, 256, CH, 256, 128, nullptr);
    gemm_f32_kernel<0, 1><<<dim3(2, CH / 64), 256, 0, stream>>>(
        g1, 256, grid_w2, grid_b2, out_gx + (size_t)c * CH * 128, 128,
        CH, 128, 256, part_g + (size_t)c * (CH / 64) * 2 * 2);
  }
  ln_finalize_kernel<<<1, 256, 0, stream>>>(part_g, NCH * (CH / 64) * 2,
                                            1.0 / ((double)GNUM * 128.0), stats_g);
  ln_apply_kernel<<<(GNUM * 128 / 4 + 255) / 256, 256, 0, stream>>>(
      gx, out_gx, grid_ln_w, grid_ln_b, stats_g, GNUM * 128 / 4);
}

// Round 2
// 939.981 us; speedup vs baseline: 1.7523x; 1.7523x over previous
//
#include <hip/hip_runtime.h>
#include <cstddef>
#include <cstdint>

constexpr int GNUM = 262144;
constexpr int MNUM = 40962;
constexpr float LN_EPS = 1e-5f;

typedef __bf16 bf16x8 __attribute__((ext_vector_type(8)));
typedef float f32x4 __attribute__((ext_vector_type(4)));

__device__ inline unsigned short f2b(float f) {
  unsigned u = __builtin_bit_cast(unsigned, f);
  u += 0x7fffu + ((u >> 16) & 1u);
  return (unsigned short)(u >> 16);
}
__device__ inline unsigned pk2(float a, float b) {
  return (unsigned)f2b(a) | ((unsigned)f2b(b) << 16);
}

// ---------- int -> float passthrough ----------
__global__ void i2f_kernel(const int* __restrict__ in, float* __restrict__ out, int n4) {
  int i = blockIdx.x * 256 + threadIdx.x;
  if (i < n4) {
    int4 v = ((const int4*)in)[i];
    ((float4*)out)[i] = make_float4((float)v.x, (float)v.y, (float)v.z, (float)v.w);
  }
}

// ---------- weight transpose + f32->bf16: W[K,N] -> Wt[N,K] ----------
__global__ void wconv_kernel(const float* __restrict__ W, unsigned short* __restrict__ Wt,
                             int K, int N) {
  int i = blockIdx.x * 256 + threadIdx.x;
  if (i >= N * K) return;
  int n = i / K, k = i - n * K;
  Wt[i] = f2b(W[(size_t)k * N + n]);
}

// ---------- scatter-add edges onto agg[MNUM,128] f32 ----------
__global__ void scatter_kernel(const float* __restrict__ ex, const int* __restrict__ col,
                               float* __restrict__ agg, int E) {
  int e = blockIdx.x * 2 + (threadIdx.x >> 7);
  int c = threadIdx.x & 127;
  if (e >= E) return;
  int m = col[e];
  unsafeAtomicAdd(&agg[(size_t)m * 128 + c], ex[(size_t)e * 128 + c]);
}

// ---------- h0b[MNUM,256] bf16 = concat(bf16(mx), bf16(agg)) ----------
__global__ void concat_kernel(const float* __restrict__ mx, const float* __restrict__ agg,
                              unsigned short* __restrict__ h0b, int total) {
  int i = blockIdx.x * 256 + threadIdx.x;  // one 8-elem group
  if (i >= total) return;
  int row = i >> 5, c8 = i & 31;
  const float* src = (c8 < 16) ? mx + (size_t)row * 128 + c8 * 8
                               : agg + (size_t)row * 128 + (c8 - 16) * 8;
  float4 v0 = *(const float4*)src;
  float4 v1 = *(const float4*)(src + 4);
  uint4 o;
  o.x = pk2(v0.x, v0.y); o.y = pk2(v0.z, v0.w);
  o.z = pk2(v1.x, v1.y); o.w = pk2(v1.z, v1.w);
  *(uint4*)(&h0b[(size_t)row * 256 + c8 * 8]) = o;
}

// ---------- bf16 MFMA GEMM ----------
// C[M,N] = act(A[M,K] @ B[K,N] + bias), B given pre-transposed bf16 Bt[N,K].
// AF32: A is f32 (convert during staging) else bf16.
// MODE 0: silu -> bf16 C.  MODE 1: plain -> f32 C + LN partial sums.
// Tile 128x128, 256 threads (4 waves, 2x2), BK=32, 4x4 16x16x32 frags/wave.
template<bool AF32, int MODE>
__global__ __launch_bounds__(256) void gemm_mfma_kernel(
    const void* __restrict__ Aptr, int lda,
    const unsigned short* __restrict__ Bt,
    const float* __restrict__ bias,
    void* __restrict__ Cptr, int ldc,
    int M, int N, int K,
    double* __restrict__ partials)
{
  __shared__ unsigned short As[128 * 32];
  __shared__ unsigned short Bs[128 * 32];
  __shared__ double red[256];

  const int t = threadIdx.x;
  const int l = t & 63, wid = t >> 6;
  const int wr = wid >> 1, wc = wid & 1;
  const int fr = l & 15, fs = l >> 4;     // fragment row/col and k-slot
  const int m0 = blockIdx.y * 128, n0 = blockIdx.x * 128;

  f32x4 acc[4][4] = {};

  for (int k0 = 0; k0 < K; k0 += 32) {
    __syncthreads();
#pragma unroll
    for (int p = 0; p < 2; ++p) {
      int q = t + p * 256;
      int row = q >> 2, s = q & 3;
      // A tile
      int gr = m0 + row;
      if (AF32) {
        float4 v0 = make_float4(0.f, 0.f, 0.f, 0.f), v1 = v0;
        if (gr < M) {
          const float* src = (const float*)Aptr + (size_t)gr * lda + k0 + s * 8;
          v0 = *(const float4*)src;
          v1 = *(const float4*)(src + 4);
        }
        uint4 o;
        o.x = pk2(v0.x, v0.y); o.y = pk2(v0.z, v0.w);
        o.z = pk2(v1.x, v1.y); o.w = pk2(v1.z, v1.w);
        *(uint4*)(&As[row * 32 + s * 8]) = o;
      } else {
        uint4 v = make_uint4(0, 0, 0, 0);
        if (gr < M)
          v = *(const uint4*)((const unsigned short*)Aptr + (size_t)gr * lda + k0 + s * 8);
        *(uint4*)(&As[row * 32 + s * 8]) = v;
      }
      // B^T tile (N % 128 == 0, no guard)
      uint4 bv = *(const uint4*)(Bt + (size_t)(n0 + row) * K + k0 + s * 8);
      *(uint4*)(&Bs[row * 32 + s * 8]) = bv;
    }
    __syncthreads();

    bf16x8 a[4], b[4];
#pragma unroll
    for (int i = 0; i < 4; ++i)
      a[i] = *(const bf16x8*)(&As[(wr * 64 + i * 16 + fr) * 32 + fs * 8]);
#pragma unroll
    for (int j = 0; j < 4; ++j)
      b[j] = *(const bf16x8*)(&Bs[(wc * 64 + j * 16 + fr) * 32 + fs * 8]);
#pragma unroll
    for (int i = 0; i < 4; ++i)
#pragma unroll
      for (int j = 0; j < 4; ++j)
        acc[i][j] = __builtin_amdgcn_mfma_f32_16x16x32_bf16(a[i], b[j], acc[i][j], 0, 0, 0);
  }

  float bcol[4];
#pragma unroll
  for (int j = 0; j < 4; ++j) bcol[j] = bias[n0 + wc * 64 + j * 16 + fr];

  float s1 = 0.f, s2 = 0.f;
#pragma unroll
  for (int i = 0; i < 4; ++i) {
#pragma unroll
    for (int r = 0; r < 4; ++r) {
      int gr = m0 + wr * 64 + i * 16 + fs * 4 + r;
      if (gr < M) {
#pragma unroll
        for (int j = 0; j < 4; ++j) {
          float x = acc[i][j][r] + bcol[j];
          int gc = n0 + wc * 64 + j * 16 + fr;
          if (MODE == 0) {
            x = x / (1.f + __expf(-x));
            ((unsigned short*)Cptr)[(size_t)gr * ldc + gc] = f2b(x);
          } else {
            ((float*)Cptr)[(size_t)gr * ldc + gc] = x;
            s1 += x; s2 += x * x;
          }
        }
      }
    }
  }

  if (MODE == 1) {
    red[t] = (double)s1;
    __syncthreads();
    for (int s = 128; s > 0; s >>= 1) { if (t < s) red[t] += red[t + s]; __syncthreads(); }
    double rs1 = red[0];
    __syncthreads();
    red[t] = (double)s2;
    __syncthreads();
    for (int s = 128; s > 0; s >>= 1) { if (t < s) red[t] += red[t + s]; __syncthreads(); }
    if (t == 0) {
      int pid = blockIdx.y * gridDim.x + blockIdx.x;
      partials[2 * pid] = rs1;
      partials[2 * pid + 1] = red[0];
    }
  }
}

// ---------- reduce partials -> (mu, rsqrt(var+eps)) ----------
__global__ void ln_finalize_kernel(const double* __restrict__ partials, int nb,
                                   double inv_count, float* __restrict__ stats) {
  __shared__ double r1[256], r2[256];
  int t = threadIdx.x;
  double s1 = 0.0, s2 = 0.0;
  for (int i = t; i < nb; i += 256) { s1 += partials[2 * i]; s2 += partials[2 * i + 1]; }
  r1[t] = s1; r2[t] = s2;
  __syncthreads();
  for (int s = 128; s > 0; s >>= 1) {
    if (t < s) { r1[t] += r1[t + s]; r2[t] += r2[t + s]; }
    __syncthreads();
  }
  if (t == 0) {
    double mu = r1[0] * inv_count;
    double var = r2[0] * inv_count - mu * mu;
    stats[0] = (float)mu;
    stats[1] = (float)(1.0 / sqrt(var + (double)LN_EPS));
  }
}

// ---------- out = base + (x - mu)*rs*w + b   (in-place in out buffer) ----------
__global__ void ln_apply_kernel(const float* __restrict__ base, float* __restrict__ x,
                                const float* __restrict__ w, const float* __restrict__ b,
                                const float* __restrict__ stats, int n4) {
  int i = blockIdx.x * 256 + threadIdx.x;
  if (i >= n4) return;
  float mu = stats[0], rs = stats[1];
  float4 xv = ((const float4*)x)[i];
  float4 bv = ((const float4*)base)[i];
  float4 wv = ((const float4*)w)[i];
  float4 bb = ((const float4*)b)[i];
  float4 o;
  o.x = bv.x + (xv.x - mu) * rs * wv.x + bb.x;
  o.y = bv.y + (xv.y - mu) * rs * wv.y + bb.y;
  o.z = bv.z + (xv.z - mu) * rs * wv.z + bb.z;
  o.w = bv.w + (xv.w - mu) * rs * wv.w + bb.w;
  ((float4*)x)[i] = o;
}

extern "C" void kernel_launch(void* const* d_in, const int* in_sizes, int n_in,
                              void* d_out, int out_size, void* d_ws, size_t ws_size,
                              hipStream_t stream) {
  const float* gx      = (const float*)d_in[0];
  const float* mx      = (const float*)d_in[1];
  const int*   me_i    = (const int*)d_in[2];
  const float* me_x    = (const float*)d_in[3];
  const int*   g2me_i  = (const int*)d_in[4];
  const float* g2me_x  = (const float*)d_in[5];
  const int*   m2ge_i  = (const int*)d_in[6];
  const float* m2ge_x  = (const float*)d_in[7];
  const float* agg_w1  = (const float*)d_in[8];
  const float* agg_b1  = (const float*)d_in[9];
  const float* agg_w2  = (const float*)d_in[10];
  const float* agg_b2  = (const float*)d_in[11];
  const float* agg_w3  = (const float*)d_in[12];
  const float* agg_b3  = (const float*)d_in[13];
  const float* agg_ln_w = (const float*)d_in[14];
  const float* agg_ln_b = (const float*)d_in[15];
  const float* grid_w1 = (const float*)d_in[16];
  const float* grid_b1 = (const float*)d_in[17];
  const float* grid_w2 = (const float*)d_in[18];
  const float* grid_b2 = (const float*)d_in[19];
  const float* grid_ln_w = (const float*)d_in[20];
  const float* grid_ln_b = (const float*)d_in[21];

  float* out = (float*)d_out;
  size_t off[9]; off[0] = 0;
  for (int i = 0; i < 8; ++i) off[i + 1] = off[i] + (size_t)in_sizes[i];
  float* out_gx  = out + off[0];
  float* out_mx  = out + off[1];
  float* out_mei = out + off[2];
  float* out_mex = out + off[3];
  float* out_g2i = out + off[4];
  float* out_g2x = out + off[5];
  float* out_m2i = out + off[6];
  float* out_m2x = out + off[7];

  const int E = in_sizes[4] / 2;

  // ---- workspace carve (~173 MB) ----
  char* wp = (char*)d_ws;
  auto carve = [&](size_t bytes) -> void* {
    void* p = (void*)wp;
    wp += (bytes + 255) & ~(size_t)255;
    return p;
  };
  float* stats_m = (float*)carve(2 * sizeof(float));
  float* stats_g = (float*)carve(2 * sizeof(float));
  const int MB_TILES = (MNUM + 127) / 128;             // 321
  double* part_m = (double*)carve((size_t)MB_TILES * 2 * sizeof(double));
  const int CH = 131072;
  const int NCH = GNUM / CH;                           // 2
  const int GB_TILES = CH / 128;                       // 1024
  double* part_g = (double*)carve((size_t)NCH * GB_TILES * 2 * sizeof(double));
  unsigned short* w1t = (unsigned short*)carve((size_t)512 * 256 * 2);
  unsigned short* w2t = (unsigned short*)carve((size_t)256 * 512 * 2);
  unsigned short* w3t = (unsigned short*)carve((size_t)128 * 256 * 2);
  unsigned short* gw1t = (unsigned short*)carve((size_t)256 * 128 * 2);
  unsigned short* gw2t = (unsigned short*)carve((size_t)128 * 256 * 2);
  float* aggbuf = (float*)carve((size_t)MNUM * 128 * 4);
  unsigned short* h0b = (unsigned short*)carve((size_t)MNUM * 256 * 2);
  unsigned short* h1b = (unsigned short*)carve((size_t)MNUM * 512 * 2);
  unsigned short* h2b = (unsigned short*)carve((size_t)MNUM * 256 * 2);
  unsigned short* g1b = (unsigned short*)carve((size_t)CH * 256 * 2);

  // ---- passthrough outputs ----
  hipMemcpyAsync(out_mex, me_x,   (size_t)in_sizes[3] * 4, hipMemcpyDeviceToDevice, stream);
  hipMemcpyAsync(out_g2x, g2me_x, (size_t)in_sizes[5] * 4, hipMemcpyDeviceToDevice, stream);
  hipMemcpyAsync(out_m2x, m2ge_x, (size_t)in_sizes[7] * 4, hipMemcpyDeviceToDevice, stream);
  i2f_kernel<<<(in_sizes[2] / 4 + 255) / 256, 256, 0, stream>>>(me_i,   out_mei, in_sizes[2] / 4);
  i2f_kernel<<<(in_sizes[4] / 4 + 255) / 256, 256, 0, stream>>>(g2me_i, out_g2i, in_sizes[4] / 4);
  i2f_kernel<<<(in_sizes[6] / 4 + 255) / 256, 256, 0, stream>>>(m2ge_i, out_m2i, in_sizes[6] / 4);

  // ---- weight conversion (tiny) ----
  wconv_kernel<<<(512 * 256 + 255) / 256, 256, 0, stream>>>(agg_w1, w1t, 256, 512);
  wconv_kernel<<<(256 * 512 + 255) / 256, 256, 0, stream>>>(agg_w2, w2t, 512, 256);
  wconv_kernel<<<(128 * 256 + 255) / 256, 256, 0, stream>>>(agg_w3, w3t, 256, 128);
  wconv_kernel<<<(256 * 128 + 255) / 256, 256, 0, stream>>>(grid_w1, gw1t, 128, 256);
  wconv_kernel<<<(128 * 256 + 255) / 256, 256, 0, stream>>>(grid_w2, gw2t, 256, 128);

  // ---- mesh path ----
  hipMemsetAsync(aggbuf, 0, (size_t)MNUM * 128 * 4, stream);
  scatter_kernel<<<(E + 1) / 2, 256, 0, stream>>>(g2me_x, g2me_i + E, aggbuf, E);
  concat_kernel<<<(MNUM * 32 + 255) / 256, 256, 0, stream>>>(mx, aggbuf, h0b, MNUM * 32);
  gemm_mfma_kernel<false, 0><<<dim3(4, MB_TILES), 256, 0, stream>>>(
      h0b, 256, w1t, agg_b1, h1b, 512, MNUM, 512, 256, nullptr);
  gemm_mfma_kernel<false, 0><<<dim3(2, MB_TILES), 256, 0, stream>>>(
      h1b, 512, w2t, agg_b2, h2b, 256, MNUM, 256, 512, nullptr);
  gemm_mfma_kernel<false, 1><<<dim3(1, MB_TILES), 256, 0, stream>>>(
      h2b, 256, w3t, agg_b3, out_mx, 128, MNUM, 128, 256, part_m);
  ln_finalize_kernel<<<1, 256, 0, stream>>>(part_m, MB_TILES,
                                            1.0 / ((double)MNUM * 128.0), stats_m);
  ln_apply_kernel<<<(MNUM * 128 / 4 + 255) / 256, 256, 0, stream>>>(
      mx, out_mx, agg_ln_w, agg_ln_b, stats_m, MNUM * 128 / 4);

  // ---- grid path (2 chunks) ----
  for (int c = 0; c < NCH; ++c) {
    const float* Ac = gx + (size_t)c * CH * 128;
    gemm_mfma_kernel<true, 0><<<dim3(2, GB_TILES), 256, 0, stream>>>(
        Ac, 128, gw1t, grid_b1, g1b, 256, CH, 256, 128, nullptr);
    gemm_mfma_kernel<false, 1><<<dim3(1, GB_TILES), 256, 0, stream>>>(
        g1b, 256, gw2t, grid_b2, out_gx + (size_t)c * CH * 128, 128,
        CH, 128, 256, part_g + (size_t)c * GB_TILES * 2);
  }
  ln_finalize_kernel<<<1, 256, 0, stream>>>(part_g, NCH * GB_TILES,
                                            1.0 / ((double)GNUM * 128.0), stats_g);
  ln_apply_kernel<<<(GNUM * 128 / 4 + 255) / 256, 256, 0, stream>>>(
      gx, out_gx, grid_ln_w, grid_ln_b, stats_g, GNUM * 128 / 4);
}

// Round 3
// 793.991 us; speedup vs baseline: 2.0745x; 1.1839x over previous
//
#include <hip/hip_runtime.h>
#include <cstddef>
#include <cstdint>

constexpr int GNUM = 262144;
constexpr int MNUM = 40962;
constexpr float LN_EPS = 1e-5f;

typedef __bf16 bf16x8 __attribute__((ext_vector_type(8)));
typedef float f32x4 __attribute__((ext_vector_type(4)));

__device__ inline unsigned short f2b(float f) {
  unsigned u = __builtin_bit_cast(unsigned, f);
  u += 0x7fffu + ((u >> 16) & 1u);
  return (unsigned short)(u >> 16);
}
__device__ inline unsigned pk2(float a, float b) {
  return (unsigned)f2b(a) | ((unsigned)f2b(b) << 16);
}
__device__ inline float b2f(unsigned short h) {
  return __builtin_bit_cast(float, (unsigned)h << 16);
}
__device__ __forceinline__ void gload16(const void* g, void* lds) {
  __builtin_amdgcn_global_load_lds(
      (const __attribute__((address_space(1))) unsigned int*)g,
      (__attribute__((address_space(3))) unsigned int*)lds, 16, 0, 0);
}

// ---------- fused int -> float passthrough (3 segments, sizes hardcoded) ----------
__global__ void i2f_all_kernel(const int* __restrict__ a, float* __restrict__ oa,
                               const int* __restrict__ b, float* __restrict__ ob,
                               const int* __restrict__ c, float* __restrict__ oc) {
  int i = blockIdx.x * 256 + threadIdx.x;
  const int N0 = 100000, N1 = 300000, N2 = 300000;  // int4 groups
  const int* src; float* dst; int j;
  if (i < N0) { src = a; dst = oa; j = i; }
  else if (i < N0 + N1) { src = b; dst = ob; j = i - N0; }
  else if (i < N0 + N1 + N2) { src = c; dst = oc; j = i - N0 - N1; }
  else return;
  int4 v = ((const int4*)src)[j];
  ((float4*)dst)[j] = make_float4((float)v.x, (float)v.y, (float)v.z, (float)v.w);
}

// ---------- fused weight transpose+convert: W[K,N] -> Wt[N,K] bf16, 5 segments ----------
__global__ void wconv_all_kernel(const float* w0, unsigned short* t0,
                                 const float* w1, unsigned short* t1,
                                 const float* w2, unsigned short* t2,
                                 const float* w3, unsigned short* t3,
                                 const float* w4, unsigned short* t4) {
  int i = blockIdx.x * 256 + threadIdx.x;
  const float* W; unsigned short* T; int K, N, j;
  if (i < 131072)      { W = w0; T = t0; K = 256; N = 512; j = i; }
  else if (i < 262144) { W = w1; T = t1; K = 512; N = 256; j = i - 131072; }
  else if (i < 294912) { W = w2; T = t2; K = 256; N = 128; j = i - 262144; }
  else if (i < 327680) { W = w3; T = t3; K = 128; N = 256; j = i - 294912; }
  else if (i < 360448) { W = w4; T = t4; K = 256; N = 128; j = i - 327680; }
  else return;
  int n = j / K, k = j - n * K;
  T[j] = f2b(W[(size_t)k * N + n]);
}

// ---------- scatter-add + passthrough copy of edge features ----------
__global__ void scatter_copy_kernel(const float* __restrict__ ex, const int* __restrict__ col,
                                    float* __restrict__ agg, float* __restrict__ out_ex, int E) {
  int e = blockIdx.x * 2 + (threadIdx.x >> 7);
  int c = threadIdx.x & 127;
  if (e >= E) return;
  size_t idx = (size_t)e * 128 + c;
  float v = ex[idx];
  out_ex[idx] = v;
  unsafeAtomicAdd(&agg[(size_t)col[e] * 128 + c], v);
}

// ---------- h0b[MNUM,256] bf16 = concat(bf16(mx), bf16(agg)) ----------
__global__ void concat_kernel(const float* __restrict__ mx, const float* __restrict__ agg,
                              unsigned short* __restrict__ h0b, int total) {
  int i = blockIdx.x * 256 + threadIdx.x;  // one 8-elem group
  if (i >= total) return;
  int row = i >> 5, c8 = i & 31;
  const float* src = (c8 < 16) ? mx + (size_t)row * 128 + c8 * 8
                               : agg + (size_t)row * 128 + (c8 - 16) * 8;
  float4 v0 = *(const float4*)src;
  float4 v1 = *(const float4*)(src + 4);
  uint4 o;
  o.x = pk2(v0.x, v0.y); o.y = pk2(v0.z, v0.w);
  o.z = pk2(v1.x, v1.y); o.w = pk2(v1.z, v1.w);
  *(uint4*)(&h0b[(size_t)row * 256 + c8 * 8]) = o;
}

// ---------- bf16 MFMA GEMM with global_load_lds staging ----------
// C = act(A @ B + bias), Bt[N,K] pre-transposed bf16.
// AF32: A is f32 (register-staged conversion). MODE 0: silu -> bf16. MODE 1: bf16 y + LN sums.
// Tile 128x128, 256 thr (4 waves 2x2), BK=32, 4x4 16x16x32 frags/wave.
template<bool AF32, int MODE>
__global__ __launch_bounds__(256) void gemm_mfma_kernel(
    const void* __restrict__ Aptr, int lda,
    const unsigned short* __restrict__ Bt,
    const float* __restrict__ bias,
    void* __restrict__ Cptr, int ldc,
    int M, int N, int K,
    double* __restrict__ partials)
{
  __shared__ unsigned short As[128 * 32];
  __shared__ unsigned short Bs[128 * 32];

  const int t = threadIdx.x;
  const int l = t & 63, wid = t >> 6;
  const int wr = wid >> 1, wc = wid & 1;
  const int fr = l & 15, fs = l >> 4;
  const int m0 = blockIdx.y * 128, n0 = blockIdx.x * 128;
  const bool fullA = (!AF32) && (m0 + 128 <= M);

  const int grow = l >> 2;        // row within a wave's 16-row group
  const int gcol = (l & 3) * 8;   // bf16 col offset within 32-wide K-slab

  f32x4 acc[4][4] = {};

  for (int k0 = 0; k0 < K; k0 += 32) {
    __syncthreads();
    // B tile: async global->LDS, 2 issues per wave (N % 128 == 0, never OOB)
#pragma unroll
    for (int p = 0; p < 2; ++p) {
      int row = wid * 16 + p * 64 + grow;
      const unsigned short* src = Bt + (size_t)(n0 + row) * K + k0 + gcol;
      gload16(src, &Bs[(wid * 16 + p * 64) * 32]);
    }
    // A tile
    if (fullA) {
#pragma unroll
      for (int p = 0; p < 2; ++p) {
        int row = wid * 16 + p * 64 + grow;
        const unsigned short* src =
            (const unsigned short*)Aptr + (size_t)(m0 + row) * lda + k0 + gcol;
        gload16(src, &As[(wid * 16 + p * 64) * 32]);
      }
    } else {
#pragma unroll
      for (int p = 0; p < 2; ++p) {
        int q = t + p * 256;
        int row = q >> 2, s = q & 3;
        int gr = m0 + row;
        if (AF32) {
          float4 v0 = make_float4(0.f, 0.f, 0.f, 0.f), v1 = v0;
          if (gr < M) {
            const float* srcf = (const float*)Aptr + (size_t)gr * lda + k0 + s * 8;
            v0 = *(const float4*)srcf;
            v1 = *(const float4*)(srcf + 4);
          }
          uint4 o;
          o.x = pk2(v0.x, v0.y); o.y = pk2(v0.z, v0.w);
          o.z = pk2(v1.x, v1.y); o.w = pk2(v1.z, v1.w);
          *(uint4*)(&As[row * 32 + s * 8]) = o;
        } else {
          uint4 v = make_uint4(0, 0, 0, 0);
          if (gr < M)
            v = *(const uint4*)((const unsigned short*)Aptr + (size_t)gr * lda + k0 + s * 8);
          *(uint4*)(&As[row * 32 + s * 8]) = v;
        }
      }
    }
    __syncthreads();

    bf16x8 a[4], b[4];
#pragma unroll
    for (int i = 0; i < 4; ++i)
      a[i] = *(const bf16x8*)(&As[(wr * 64 + i * 16 + fr) * 32 + fs * 8]);
#pragma unroll
    for (int j = 0; j < 4; ++j)
      b[j] = *(const bf16x8*)(&Bs[(wc * 64 + j * 16 + fr) * 32 + fs * 8]);
#pragma unroll
    for (int i = 0; i < 4; ++i)
#pragma unroll
      for (int j = 0; j < 4; ++j)
        acc[i][j] = __builtin_amdgcn_mfma_f32_16x16x32_bf16(a[i], b[j], acc[i][j], 0, 0, 0);
  }

  float bcol[4];
#pragma unroll
  for (int j = 0; j < 4; ++j) bcol[j] = bias[n0 + wc * 64 + j * 16 + fr];

  float s1 = 0.f, s2 = 0.f;
#pragma unroll
  for (int i = 0; i < 4; ++i) {
#pragma unroll
    for (int r = 0; r < 4; ++r) {
      int gr = m0 + wr * 64 + i * 16 + fs * 4 + r;
      if (gr < M) {
#pragma unroll
        for (int j = 0; j < 4; ++j) {
          float x = acc[i][j][r] + bcol[j];
          int gc = n0 + wc * 64 + j * 16 + fr;
          if constexpr (MODE == 0) {
            x = x / (1.f + __expf(-x));
            ((unsigned short*)Cptr)[(size_t)gr * ldc + gc] = f2b(x);
          } else {
            ((unsigned short*)Cptr)[(size_t)gr * ldc + gc] = f2b(x);
            s1 += x; s2 += x * x;
          }
        }
      }
    }
  }

  if constexpr (MODE == 1) {
    __shared__ double red[256];
    red[t] = (double)s1;
    __syncthreads();
    for (int s = 128; s > 0; s >>= 1) { if (t < s) red[t] += red[t + s]; __syncthreads(); }
    double rs1 = red[0];
    __syncthreads();
    red[t] = (double)s2;
    __syncthreads();
    for (int s = 128; s > 0; s >>= 1) { if (t < s) red[t] += red[t + s]; __syncthreads(); }
    if (t == 0) {
      int pid = blockIdx.y * gridDim.x + blockIdx.x;
      partials[2 * pid] = rs1;
      partials[2 * pid + 1] = red[0];
    }
  }
}

// ---------- reduce partials -> (mu, rsqrt(var+eps)) ----------
__global__ void ln_finalize_kernel(const double* __restrict__ partials, int nb,
                                   double inv_count, float* __restrict__ stats) {
  __shared__ double r1[256], r2[256];
  int t = threadIdx.x;
  double s1 = 0.0, s2 = 0.0;
  for (int i = t; i < nb; i += 256) { s1 += partials[2 * i]; s2 += partials[2 * i + 1]; }
  r1[t] = s1; r2[t] = s2;
  __syncthreads();
  for (int s = 128; s > 0; s >>= 1) {
    if (t < s) { r1[t] += r1[t + s]; r2[t] += r2[t + s]; }
    __syncthreads();
  }
  if (t == 0) {
    double mu = r1[0] * inv_count;
    double var = r2[0] * inv_count - mu * mu;
    stats[0] = (float)mu;
    stats[1] = (float)(1.0 / sqrt(var + (double)LN_EPS));
  }
}

// ---------- out = base + (bf16(y) - mu)*rs*w + b ----------
__global__ void ln_apply_b_kernel(const float* __restrict__ base,
                                  const unsigned short* __restrict__ y,
                                  const float* __restrict__ w, const float* __restrict__ b,
                                  const float* __restrict__ stats,
                                  float* __restrict__ outp, int n4) {
  int i = blockIdx.x * 256 + threadIdx.x;
  if (i >= n4) return;
  float mu = stats[0], rs = stats[1];
  ushort4 yv = ((const ushort4*)y)[i];
  float4 bv = ((const float4*)base)[i];
  float4 wv = ((const float4*)w)[i];
  float4 bb = ((const float4*)b)[i];
  float4 o;
  o.x = bv.x + (b2f(yv.x) - mu) * rs * wv.x + bb.x;
  o.y = bv.y + (b2f(yv.y) - mu) * rs * wv.y + bb.y;
  o.z = bv.z + (b2f(yv.z) - mu) * rs * wv.z + bb.z;
  o.w = bv.w + (b2f(yv.w) - mu) * rs * wv.w + bb.w;
  ((float4*)outp)[i] = o;
}

extern "C" void kernel_launch(void* const* d_in, const int* in_sizes, int n_in,
                              void* d_out, int out_size, void* d_ws, size_t ws_size,
                              hipStream_t stream) {
  const float* gx      = (const float*)d_in[0];
  const float* mx      = (const float*)d_in[1];
  const int*   me_i    = (const int*)d_in[2];
  const float* me_x    = (const float*)d_in[3];
  const int*   g2me_i  = (const int*)d_in[4];
  const float* g2me_x  = (const float*)d_in[5];
  const int*   m2ge_i  = (const int*)d_in[6];
  const float* m2ge_x  = (const float*)d_in[7];
  const float* agg_w1  = (const float*)d_in[8];
  const float* agg_b1  = (const float*)d_in[9];
  const float* agg_w2  = (const float*)d_in[10];
  const float* agg_b2  = (const float*)d_in[11];
  const float* agg_w3  = (const float*)d_in[12];
  const float* agg_b3  = (const float*)d_in[13];
  const float* agg_ln_w = (const float*)d_in[14];
  const float* agg_ln_b = (const float*)d_in[15];
  const float* grid_w1 = (const float*)d_in[16];
  const float* grid_b1 = (const float*)d_in[17];
  const float* grid_w2 = (const float*)d_in[18];
  const float* grid_b2 = (const float*)d_in[19];
  const float* grid_ln_w = (const float*)d_in[20];
  const float* grid_ln_b = (const float*)d_in[21];

  float* out = (float*)d_out;
  size_t off[9]; off[0] = 0;
  for (int i = 0; i < 8; ++i) off[i + 1] = off[i] + (size_t)in_sizes[i];
  float* out_gx  = out + off[0];
  float* out_mx  = out + off[1];
  float* out_mei = out + off[2];
  float* out_mex = out + off[3];
  float* out_g2i = out + off[4];
  float* out_g2x = out + off[5];
  float* out_m2i = out + off[6];
  float* out_m2x = out + off[7];

  const int E = in_sizes[4] / 2;

  // ---- workspace carve ----
  char* wp = (char*)d_ws;
  auto carve = [&](size_t bytes) -> void* {
    void* p = (void*)wp;
    wp += (bytes + 255) & ~(size_t)255;
    return p;
  };
  float* stats_m = (float*)carve(2 * sizeof(float));
  float* stats_g = (float*)carve(2 * sizeof(float));
  const int MB_TILES = (MNUM + 127) / 128;             // 321
  double* part_m = (double*)carve((size_t)MB_TILES * 2 * sizeof(double));
  const int CH = 131072;
  const int NCH = GNUM / CH;                           // 2
  const int GB_TILES = CH / 128;                       // 1024
  double* part_g = (double*)carve((size_t)NCH * GB_TILES * 2 * sizeof(double));
  unsigned short* w1t = (unsigned short*)carve((size_t)512 * 256 * 2);
  unsigned short* w2t = (unsigned short*)carve((size_t)256 * 512 * 2);
  unsigned short* w3t = (unsigned short*)carve((size_t)128 * 256 * 2);
  unsigned short* gw1t = (unsigned short*)carve((size_t)256 * 128 * 2);
  unsigned short* gw2t = (unsigned short*)carve((size_t)128 * 256 * 2);
  float* aggbuf = (float*)carve((size_t)MNUM * 128 * 4);
  unsigned short* h0b = (unsigned short*)carve((size_t)MNUM * 256 * 2);
  unsigned short* h1b = (unsigned short*)carve((size_t)MNUM * 512 * 2);
  unsigned short* h2b = (unsigned short*)carve((size_t)MNUM * 256 * 2);
  unsigned short* g1b = (unsigned short*)carve((size_t)CH * 256 * 2);
  unsigned short* ym  = (unsigned short*)carve((size_t)MNUM * 128 * 2);
  unsigned short* yg  = (unsigned short*)carve((size_t)GNUM * 128 * 2);

  // ---- passthrough outputs (g2me_x copy fused into scatter below) ----
  hipMemcpyAsync(out_mex, me_x,   (size_t)in_sizes[3] * 4, hipMemcpyDeviceToDevice, stream);
  hipMemcpyAsync(out_m2x, m2ge_x, (size_t)in_sizes[7] * 4, hipMemcpyDeviceToDevice, stream);
  i2f_all_kernel<<<(700000 + 255) / 256, 256, 0, stream>>>(
      me_i, out_mei, g2me_i, out_g2i, m2ge_i, out_m2i);
  wconv_all_kernel<<<(360448 + 255) / 256, 256, 0, stream>>>(
      agg_w1, w1t, agg_w2, w2t, agg_w3, w3t, grid_w1, gw1t, grid_w2, gw2t);

  // ---- mesh path ----
  hipMemsetAsync(aggbuf, 0, (size_t)MNUM * 128 * 4, stream);
  scatter_copy_kernel<<<(E + 1) / 2, 256, 0, stream>>>(g2me_x, g2me_i + E, aggbuf, out_g2x, E);
  concat_kernel<<<(MNUM * 32 + 255) / 256, 256, 0, stream>>>(mx, aggbuf, h0b, MNUM * 32);
  gemm_mfma_kernel<false, 0><<<dim3(4, MB_TILES), 256, 0, stream>>>(
      h0b, 256, w1t, agg_b1, h1b, 512, MNUM, 512, 256, nullptr);
  gemm_mfma_kernel<false, 0><<<dim3(2, MB_TILES), 256, 0, stream>>>(
      h1b, 512, w2t, agg_b2, h2b, 256, MNUM, 256, 512, nullptr);
  gemm_mfma_kernel<false, 1><<<dim3(1, MB_TILES), 256, 0, stream>>>(
      h2b, 256, w3t, agg_b3, ym, 128, MNUM, 128, 256, part_m);
  ln_finalize_kernel<<<1, 256, 0, stream>>>(part_m, MB_TILES,
                                            1.0 / ((double)MNUM * 128.0), stats_m);
  ln_apply_b_kernel<<<(MNUM * 128 / 4 + 255) / 256, 256, 0, stream>>>(
      mx, ym, agg_ln_w, agg_ln_b, stats_m, out_mx, MNUM * 128 / 4);

  // ---- grid path (2 chunks) ----
  for (int c = 0; c < NCH; ++c) {
    const float* Ac = gx + (size_t)c * CH * 128;
    gemm_mfma_kernel<true, 0><<<dim3(2, GB_TILES), 256, 0, stream>>>(
        Ac, 128, gw1t, grid_b1, g1b, 256, CH, 256, 128, nullptr);
    gemm_mfma_kernel<false, 1><<<dim3(1, GB_TILES), 256, 0, stream>>>(
        g1b, 256, gw2t, grid_b2, yg + (size_t)c * CH * 128, 128,
        CH, 128, 256, part_g + (size_t)c * GB_TILES * 2);
  }
  ln_finalize_kernel<<<1, 256, 0, stream>>>(part_g, NCH * GB_TILES,
                                            1.0 / ((double)GNUM * 128.0), stats_g);
  ln_apply_b_kernel<<<(GNUM * 128 / 4 + 255) / 256, 256, 0, stream>>>(
      gx, yg, grid_ln_w, grid_ln_b, stats_g, out_gx, GNUM * 128 / 4);
}

// Round 4
// 765.885 us; speedup vs baseline: 2.1506x; 1.0367x over previous
//
#include <hip/hip_runtime.h>
#include <cstddef>
#include <cstdint>

constexpr int GNUM = 262144;
constexpr int MNUM = 40962;
constexpr float LN_EPS = 1e-5f;

typedef __bf16 bf16x8 __attribute__((ext_vector_type(8)));
typedef float f32x4 __attribute__((ext_vector_type(4)));

__device__ inline unsigned short f2b(float f) {
  unsigned u = __builtin_bit_cast(unsigned, f);
  u += 0x7fffu + ((u >> 16) & 1u);
  return (unsigned short)(u >> 16);
}
__device__ inline unsigned pk2(float a, float b) {
  return (unsigned)f2b(a) | ((unsigned)f2b(b) << 16);
}
__device__ inline float b2f(unsigned short h) {
  return __builtin_bit_cast(float, (unsigned)h << 16);
}
__device__ __forceinline__ void gload16(const void* g, void* lds) {
  __builtin_amdgcn_global_load_lds(
      (const __attribute__((address_space(1))) unsigned int*)g,
      (__attribute__((address_space(3))) unsigned int*)lds, 16, 0, 0);
}

// ---------- one fused aux kernel: 2 big copies + 3 i2f + 5 wconv ----------
__global__ void aux_kernel(
    const float4* __restrict__ c1s, float4* __restrict__ c1d, int n1,
    const float4* __restrict__ c2s, float4* __restrict__ c2d, int n2,
    const int4* __restrict__ ia, float4* __restrict__ oa, int na,
    const int4* __restrict__ ib, float4* __restrict__ ob, int nbv,
    const int4* __restrict__ ic, float4* __restrict__ oc, int nc,
    const float* __restrict__ w0, unsigned short* __restrict__ t0,
    const float* __restrict__ w1, unsigned short* __restrict__ t1,
    const float* __restrict__ w2, unsigned short* __restrict__ t2,
    const float* __restrict__ w3, unsigned short* __restrict__ t3,
    const float* __restrict__ w4, unsigned short* __restrict__ t4) {
  int i = blockIdx.x * 256 + threadIdx.x;
  int b0 = n1, b1 = b0 + n2, b2 = b1 + na, b3 = b2 + nbv, b4 = b3 + nc;
  if (i < b0) { c1d[i] = c1s[i]; return; }
  if (i < b1) { int j = i - b0; c2d[j] = c2s[j]; return; }
  if (i < b4) {
    const int4* src; float4* dst; int j;
    if (i < b2)      { src = ia; dst = oa; j = i - b1; }
    else if (i < b3) { src = ib; dst = ob; j = i - b2; }
    else             { src = ic; dst = oc; j = i - b3; }
    int4 v = src[j];
    dst[j] = make_float4((float)v.x, (float)v.y, (float)v.z, (float)v.w);
    return;
  }
  int j = i - b4;
  const float* W; unsigned short* T; int K, N;
  if (j < 131072)      { W = w0; T = t0; K = 256; N = 512; }
  else if (j < 262144) { W = w1; T = t1; K = 512; N = 256; j -= 131072; }
  else if (j < 294912) { W = w2; T = t2; K = 256; N = 128; j -= 262144; }
  else if (j < 327680) { W = w3; T = t3; K = 128; N = 256; j -= 294912; }
  else if (j < 360448) { W = w4; T = t4; K = 256; N = 128; j -= 327680; }
  else return;
  int n = j / K, k = j - n * K;
  T[j] = f2b(W[(size_t)k * N + n]);
}

// ---------- scatter-add + passthrough copy of edge features ----------
__global__ void scatter_copy_kernel(const float* __restrict__ ex, const int* __restrict__ col,
                                    float* __restrict__ agg, float* __restrict__ out_ex, int E) {
  int e = blockIdx.x * 2 + (threadIdx.x >> 7);
  int c = threadIdx.x & 127;
  if (e >= E) return;
  size_t idx = (size_t)e * 128 + c;
  float v = ex[idx];
  out_ex[idx] = v;
  unsafeAtomicAdd(&agg[(size_t)col[e] * 128 + c], v);
}

// ---------- h0b[MNUM,256] bf16 = concat(bf16(mx), bf16(agg)) ----------
__global__ void concat_kernel(const float* __restrict__ mx, const float* __restrict__ agg,
                              unsigned short* __restrict__ h0b, int total) {
  int i = blockIdx.x * 256 + threadIdx.x;  // one 8-elem group
  if (i >= total) return;
  int row = i >> 5, c8 = i & 31;
  const float* src = (c8 < 16) ? mx + (size_t)row * 128 + c8 * 8
                               : agg + (size_t)row * 128 + (c8 - 16) * 8;
  float4 v0 = *(const float4*)src;
  float4 v1 = *(const float4*)(src + 4);
  uint4 o;
  o.x = pk2(v0.x, v0.y); o.y = pk2(v0.z, v0.w);
  o.z = pk2(v1.x, v1.y); o.w = pk2(v1.z, v1.w);
  *(uint4*)(&h0b[(size_t)row * 256 + c8 * 8]) = o;
}

// ---------- bf16 MFMA GEMM, global_load_lds staging, XOR-swizzled LDS ----------
// LDS layout: tile[row][32] bf16 (64B rows, 4 x 16B slabs). Stored slab j holds
// global slab (j ^ sw(row)), sw(row) = (row>>1)&3  -> 2-way residual conflict.
template<bool AF32, int MODE>
__global__ __launch_bounds__(256) void gemm_mfma_kernel(
    const void* __restrict__ Aptr, int lda,
    const unsigned short* __restrict__ Bt,
    const float* __restrict__ bias,
    void* __restrict__ Cptr, int ldc,
    int M, int N, int K,
    double* __restrict__ partials)
{
  __shared__ unsigned short As[128 * 32];
  __shared__ unsigned short Bs[128 * 32];

  const int t = threadIdx.x;
  const int l = t & 63, wid = t >> 6;
  const int wr = wid >> 1, wc = wid & 1;
  const int fr = l & 15, fs = l >> 4;
  const int m0 = blockIdx.y * 128, n0 = blockIdx.x * 128;
  const bool fullA = (!AF32) && (m0 + 128 <= M);

  const int grow = l >> 2;                              // row within 16-row group
  const int gslab = ((l & 3) ^ ((l >> 3) & 3)) * 8;     // pre-swizzled source slab
  const int rsw = (fr >> 1) & 3;                        // read-side swizzle

  f32x4 acc[4][4] = {};

  for (int k0 = 0; k0 < K; k0 += 32) {
    __syncthreads();
    // B tile: async global->LDS (N%128==0, never OOB), source slab pre-swizzled
#pragma unroll
    for (int p = 0; p < 2; ++p) {
      int row0 = wid * 16 + p * 64;
      const unsigned short* src = Bt + (size_t)(n0 + row0 + grow) * K + k0 + gslab;
      gload16(src, &Bs[row0 * 32]);
    }
    // A tile
    if (fullA) {
#pragma unroll
      for (int p = 0; p < 2; ++p) {
        int row0 = wid * 16 + p * 64;
        const unsigned short* src =
            (const unsigned short*)Aptr + (size_t)(m0 + row0 + grow) * lda + k0 + gslab;
        gload16(src, &As[row0 * 32]);
      }
    } else {
#pragma unroll
      for (int p = 0; p < 2; ++p) {
        int q = t + p * 256;
        int row = q >> 2, s = q & 3;
        int js = (s ^ ((row >> 1) & 3)) * 8;   // store to swizzled slab
        int gr = m0 + row;
        if (AF32) {
          float4 v0 = make_float4(0.f, 0.f, 0.f, 0.f), v1 = v0;
          if (gr < M) {
            const float* srcf = (const float*)Aptr + (size_t)gr * lda + k0 + s * 8;
            v0 = *(const float4*)srcf;
            v1 = *(const float4*)(srcf + 4);
          }
          uint4 o;
          o.x = pk2(v0.x, v0.y); o.y = pk2(v0.z, v0.w);
          o.z = pk2(v1.x, v1.y); o.w = pk2(v1.z, v1.w);
          *(uint4*)(&As[row * 32 + js]) = o;
        } else {
          uint4 v = make_uint4(0, 0, 0, 0);
          if (gr < M)
            v = *(const uint4*)((const unsigned short*)Aptr + (size_t)gr * lda + k0 + s * 8);
          *(uint4*)(&As[row * 32 + js]) = v;
        }
      }
    }
    __syncthreads();

    bf16x8 a[4], b[4];
#pragma unroll
    for (int i = 0; i < 4; ++i)
      a[i] = *(const bf16x8*)(&As[(wr * 64 + i * 16 + fr) * 32 + (fs ^ rsw) * 8]);
#pragma unroll
    for (int j = 0; j < 4; ++j)
      b[j] = *(const bf16x8*)(&Bs[(wc * 64 + j * 16 + fr) * 32 + (fs ^ rsw) * 8]);
#pragma unroll
    for (int i = 0; i < 4; ++i)
#pragma unroll
      for (int j = 0; j < 4; ++j)
        acc[i][j] = __builtin_amdgcn_mfma_f32_16x16x32_bf16(a[i], b[j], acc[i][j], 0, 0, 0);
  }

  float bcol[4];
#pragma unroll
  for (int j = 0; j < 4; ++j) bcol[j] = bias[n0 + wc * 64 + j * 16 + fr];

  float s1 = 0.f, s2 = 0.f;
#pragma unroll
  for (int i = 0; i < 4; ++i) {
#pragma unroll
    for (int r = 0; r < 4; ++r) {
      int gr = m0 + wr * 64 + i * 16 + fs * 4 + r;
      if (gr < M) {
#pragma unroll
        for (int j = 0; j < 4; ++j) {
          float x = acc[i][j][r] + bcol[j];
          int gc = n0 + wc * 64 + j * 16 + fr;
          if constexpr (MODE == 0) {
            x = x / (1.f + __expf(-x));
            ((unsigned short*)Cptr)[(size_t)gr * ldc + gc] = f2b(x);
          } else {
            ((unsigned short*)Cptr)[(size_t)gr * ldc + gc] = f2b(x);
            s1 += x; s2 += x * x;
          }
        }
      }
    }
  }

  if constexpr (MODE == 1) {
    __shared__ double red[256];
    red[t] = (double)s1;
    __syncthreads();
    for (int s = 128; s > 0; s >>= 1) { if (t < s) red[t] += red[t + s]; __syncthreads(); }
    double rs1 = red[0];
    __syncthreads();
    red[t] = (double)s2;
    __syncthreads();
    for (int s = 128; s > 0; s >>= 1) { if (t < s) red[t] += red[t + s]; __syncthreads(); }
    if (t == 0) {
      int pid = blockIdx.y * gridDim.x + blockIdx.x;
      partials[2 * pid] = rs1;
      partials[2 * pid + 1] = red[0];
    }
  }
}

// ---------- grid-stride LN apply with in-block partials reduction ----------
// out = base + (bf16(y) - mu)*rs*w + b
__global__ void ln_apply_b_kernel(const float* __restrict__ base,
                                  const unsigned short* __restrict__ y,
                                  const float* __restrict__ w, const float* __restrict__ b,
                                  const double* __restrict__ partials, int nb,
                                  double inv_count,
                                  float* __restrict__ outp, int n4) {
  __shared__ double r1[256], r2[256];
  __shared__ float sstat[2];
  int t = threadIdx.x;
  double s1 = 0.0, s2 = 0.0;
  for (int i = t; i < nb; i += 256) { s1 += partials[2 * i]; s2 += partials[2 * i + 1]; }
  r1[t] = s1; r2[t] = s2;
  __syncthreads();
  for (int s = 128; s > 0; s >>= 1) {
    if (t < s) { r1[t] += r1[t + s]; r2[t] += r2[t + s]; }
    __syncthreads();
  }
  if (t == 0) {
    double mu = r1[0] * inv_count;
    double var = r2[0] * inv_count - mu * mu;
    sstat[0] = (float)mu;
    sstat[1] = (float)(1.0 / sqrt(var + (double)LN_EPS));
  }
  __syncthreads();
  float mu = sstat[0], rs = sstat[1];
  for (int i = blockIdx.x * 256 + t; i < n4; i += gridDim.x * 256) {
    ushort4 yv = ((const ushort4*)y)[i];
    float4 bv = ((const float4*)base)[i];
    float4 wv = ((const float4*)w)[i];
    float4 bb = ((const float4*)b)[i];
    float4 o;
    o.x = bv.x + (b2f(yv.x) - mu) * rs * wv.x + bb.x;
    o.y = bv.y + (b2f(yv.y) - mu) * rs * wv.y + bb.y;
    o.z = bv.z + (b2f(yv.z) - mu) * rs * wv.z + bb.z;
    o.w = bv.w + (b2f(yv.w) - mu) * rs * wv.w + bb.w;
    ((float4*)outp)[i] = o;
  }
}

extern "C" void kernel_launch(void* const* d_in, const int* in_sizes, int n_in,
                              void* d_out, int out_size, void* d_ws, size_t ws_size,
                              hipStream_t stream) {
  const float* gx      = (const float*)d_in[0];
  const float* mx      = (const float*)d_in[1];
  const int*   me_i    = (const int*)d_in[2];
  const float* me_x    = (const float*)d_in[3];
  const int*   g2me_i  = (const int*)d_in[4];
  const float* g2me_x  = (const float*)d_in[5];
  const int*   m2ge_i  = (const int*)d_in[6];
  const float* m2ge_x  = (const float*)d_in[7];
  const float* agg_w1  = (const float*)d_in[8];
  const float* agg_b1  = (const float*)d_in[9];
  const float* agg_w2  = (const float*)d_in[10];
  const float* agg_b2  = (const float*)d_in[11];
  const float* agg_w3  = (const float*)d_in[12];
  const float* agg_b3  = (const float*)d_in[13];
  const float* agg_ln_w = (const float*)d_in[14];
  const float* agg_ln_b = (const float*)d_in[15];
  const float* grid_w1 = (const float*)d_in[16];
  const float* grid_b1 = (const float*)d_in[17];
  const float* grid_w2 = (const float*)d_in[18];
  const float* grid_b2 = (const float*)d_in[19];
  const float* grid_ln_w = (const float*)d_in[20];
  const float* grid_ln_b = (const float*)d_in[21];

  float* out = (float*)d_out;
  size_t off[9]; off[0] = 0;
  for (int i = 0; i < 8; ++i) off[i + 1] = off[i] + (size_t)in_sizes[i];
  float* out_gx  = out + off[0];
  float* out_mx  = out + off[1];
  float* out_mei = out + off[2];
  float* out_mex = out + off[3];
  float* out_g2i = out + off[4];
  float* out_g2x = out + off[5];
  float* out_m2i = out + off[6];
  float* out_m2x = out + off[7];

  const int E = in_sizes[4] / 2;

  // ---- workspace carve ----
  char* wp = (char*)d_ws;
  auto carve = [&](size_t bytes) -> void* {
    void* p = (void*)wp;
    wp += (bytes + 255) & ~(size_t)255;
    return p;
  };
  const int MB_TILES = (MNUM + 127) / 128;             // 321
  double* part_m = (double*)carve((size_t)MB_TILES * 2 * sizeof(double));
  const int CH = 131072;
  const int NCH = GNUM / CH;                           // 2
  const int GB_TILES = CH / 128;                       // 1024
  double* part_g = (double*)carve((size_t)NCH * GB_TILES * 2 * sizeof(double));
  unsigned short* w1t = (unsigned short*)carve((size_t)512 * 256 * 2);
  unsigned short* w2t = (unsigned short*)carve((size_t)256 * 512 * 2);
  unsigned short* w3t = (unsigned short*)carve((size_t)128 * 256 * 2);
  unsigned short* gw1t = (unsigned short*)carve((size_t)256 * 128 * 2);
  unsigned short* gw2t = (unsigned short*)carve((size_t)128 * 256 * 2);
  float* aggbuf = (float*)carve((size_t)MNUM * 128 * 4);
  unsigned short* h0b = (unsigned short*)carve((size_t)MNUM * 256 * 2);
  unsigned short* h1b = (unsigned short*)carve((size_t)MNUM * 512 * 2);
  unsigned short* h2b = (unsigned short*)carve((size_t)MNUM * 256 * 2);
  unsigned short* g1b = (unsigned short*)carve((size_t)CH * 256 * 2);
  unsigned short* ym  = (unsigned short*)carve((size_t)MNUM * 128 * 2);
  unsigned short* yg  = (unsigned short*)carve((size_t)GNUM * 128 * 2);

  // ---- aux: big copies + i2f + wconv in one kernel ----
  {
    int n1 = in_sizes[3] / 4;        // me_x float4
    int n2 = in_sizes[7] / 4;        // m2ge_x float4
    int na = in_sizes[2] / 4, nbv = in_sizes[4] / 4, nc = in_sizes[6] / 4;
    long total = (long)n1 + n2 + na + nbv + nc + 360448;
    aux_kernel<<<(int)((total + 255) / 256), 256, 0, stream>>>(
        (const float4*)me_x, (float4*)out_mex, n1,
        (const float4*)m2ge_x, (float4*)out_m2x, n2,
        (const int4*)me_i, (float4*)out_mei, na,
        (const int4*)g2me_i, (float4*)out_g2i, nbv,
        (const int4*)m2ge_i, (float4*)out_m2i, nc,
        agg_w1, w1t, agg_w2, w2t, agg_w3, w3t, grid_w1, gw1t, grid_w2, gw2t);
  }

  // ---- mesh path ----
  hipMemsetAsync(aggbuf, 0, (size_t)MNUM * 128 * 4, stream);
  scatter_copy_kernel<<<(E + 1) / 2, 256, 0, stream>>>(g2me_x, g2me_i + E, aggbuf, out_g2x, E);
  concat_kernel<<<(MNUM * 32 + 255) / 256, 256, 0, stream>>>(mx, aggbuf, h0b, MNUM * 32);
  gemm_mfma_kernel<false, 0><<<dim3(4, MB_TILES), 256, 0, stream>>>(
      h0b, 256, w1t, agg_b1, h1b, 512, MNUM, 512, 256, nullptr);
  gemm_mfma_kernel<false, 0><<<dim3(2, MB_TILES), 256, 0, stream>>>(
      h1b, 512, w2t, agg_b2, h2b, 256, MNUM, 256, 512, nullptr);
  gemm_mfma_kernel<false, 1><<<dim3(1, MB_TILES), 256, 0, stream>>>(
      h2b, 256, w3t, agg_b3, ym, 128, MNUM, 128, 256, part_m);
  ln_apply_b_kernel<<<1024, 256, 0, stream>>>(
      mx, ym, agg_ln_w, agg_ln_b, part_m, MB_TILES,
      1.0 / ((double)MNUM * 128.0), out_mx, MNUM * 128 / 4);

  // ---- grid path (2 chunks) ----
  for (int c = 0; c < NCH; ++c) {
    const float* Ac = gx + (size_t)c * CH * 128;
    gemm_mfma_kernel<true, 0><<<dim3(2, GB_TILES), 256, 0, stream>>>(
        Ac, 128, gw1t, grid_b1, g1b, 256, CH, 256, 128, nullptr);
    gemm_mfma_kernel<false, 1><<<dim3(1, GB_TILES), 256, 0, stream>>>(
        g1b, 256, gw2t, grid_b2, yg + (size_t)c * CH * 128, 128,
        CH, 128, 256, part_g + (size_t)c * GB_TILES * 2);
  }
  ln_apply_b_kernel<<<2048, 256, 0, stream>>>(
      gx, yg, grid_ln_w, grid_ln_b, part_g, NCH * GB_TILES,
      1.0 / ((double)GNUM * 128.0), out_gx, GNUM * 128 / 4);
}